// Round 16
// baseline (173.403 us; speedup 1.0000x reference)
//
#include <hip/hip_runtime.h>

// GraphSAGE layer: B=8, N=5000, E=100000, D=128. All float tensors f32; edge_index int32.
// R16 pipeline (4 dispatches): memset(cnt) -> fill (XCD-affine buckets + x->bf16 conv
//   + packW) -> gather (STANDALONE, 1 wave/node, 40K waves) -> gemm_ln (MFMA + LN).
// R15 post-mortem: two ILP doublings (R13, R15) both neutral -> the "gather is
// load-chain latency-bound" model is wrong at resource level (bottom-up: ~6us L2 BW,
// ~4us VALU, ~5us TA). Split restores attribution AND tests the TLP hypothesis:
// standalone gather gets 40K waves (4x the fused concurrency, R5-style grid) while
// keeping R13's 16-lane/uint4/16-deep inner loop.

#define B_ 8
#define N_ 5000
#define E_ 100000
#define D_ 128
#define EPS_ 1e-5f
#define NNODES (B_ * N_)   // 40000
#define NEDGES (B_ * E_)   // 800000
#define JB 313             // 16-node blocks per batch (312*16+8 = 5000)
#define EPB ((E_ + 255) / 256)        // 391 edge-blocks per batch (ceil — R9 lesson)
#define FILL_BLOCKS (8 * EPB)         // 3128
#define CONV_BLOCKS 2500              // x -> bf16: 2048 elems/block
#define CAP 64             // bucket capacity per node (avg deg 20, P(ovf) ~ 5e-14)
#define LDSP 136           // padded bf16 row stride (272 B -> 2-way bank alias, free)

typedef __bf16 bf16x8 __attribute__((ext_vector_type(8)));
typedef float  f32x4  __attribute__((ext_vector_type(4)));

static __device__ __forceinline__ unsigned short f2bf(float f) {
    union { float f; unsigned int i; } c; c.f = f;
    unsigned int i = c.i;
    i += 0x7fffu + ((i >> 16) & 1u);
    return (unsigned short)(i >> 16);
}
static __device__ __forceinline__ float bflo(unsigned int u) {
    return __uint_as_float(u << 16);
}
static __device__ __forceinline__ float bfhi(unsigned int u) {
    return __uint_as_float(u & 0xffff0000u);
}

// ---------- fill: XCD-affine buckets (0..3127) + x->bf16 (3128..5627) + packW ----------
__global__ __launch_bounds__(256) void fill_k(
    const int* __restrict__ ei, const float* __restrict__ em,
    int* __restrict__ cnt, int2* __restrict__ entries,
    const float* __restrict__ x, unsigned short* __restrict__ xbf,
    const float* __restrict__ Wself, const float* __restrict__ Wnb,
    unsigned short* __restrict__ Bt)
{
    int blk = blockIdx.x;
    if (blk < FILL_BLOCKS) {
        int b = blk & 7;                    // batch -> XCD (round-robin dispatch)
        int e = (blk >> 3) * 256 + threadIdx.x;
        if (e >= E_) return;
        const int* eib = ei + (size_t)b * 2 * E_;
        int src = eib[e];
        int tgt = eib[E_ + e];
        float m = em[(size_t)b * E_ + e];
        if (m != 0.0f) {
            int g = b * N_ + tgt;
            int slot = atomicAdd(&cnt[g], 1);
            if (slot < CAP)
                entries[((size_t)g << 6) + slot] =
                    make_int2(b * N_ + src, __float_as_int(m));
        }
    } else if (blk < FILL_BLOCKS + CONV_BLOCKS) {
        size_t base = (size_t)(blk - FILL_BLOCKS) * 2048 + threadIdx.x * 8;
        float4 va = *(const float4*)(x + base);
        float4 vb = *(const float4*)(x + base + 4);
        uint4 o;
        o.x = (unsigned int)f2bf(va.x) | ((unsigned int)f2bf(va.y) << 16);
        o.y = (unsigned int)f2bf(va.z) | ((unsigned int)f2bf(va.w) << 16);
        o.z = (unsigned int)f2bf(vb.x) | ((unsigned int)f2bf(vb.y) << 16);
        o.w = (unsigned int)f2bf(vb.z) | ((unsigned int)f2bf(vb.w) << 16);
        *(uint4*)(xbf + base) = o;
    } else {
        int n = blk - FILL_BLOCKS - CONV_BLOCKS;   // 0..127
        int k = threadIdx.x;                       // 0..255
        float v = (k < 128) ? Wself[(size_t)k * D_ + n]
                            : Wnb[(size_t)(k - 128) * D_ + n];
        Bt[(size_t)n * 256 + k] = f2bf(v);
    }
}

// ---------- gather: STANDALONE, one wave per node (40K waves), R13 inner loop ----------
// Grid 1250*8; blk&7 = batch (XCD affinity); node = (blk>>3)*4 + wave.
__global__ __launch_bounds__(256) void gather_k(
    const unsigned short* __restrict__ xbf, const int* __restrict__ cnt,
    const int2* __restrict__ entries, unsigned short* __restrict__ agg)
{
    int wv = threadIdx.x >> 6, lane = threadIdx.x & 63;
    int b = blockIdx.x & 7;
    int i = (blockIdx.x >> 3) * 4 + wv;    // 0..4999 exact (1250*4 = 5000)
    int g = b * N_ + i;

    int dg = cnt[g]; if (dg > CAP) dg = CAP;
    const int2* ep = entries + ((size_t)g << 6);
    int grp = lane >> 4;                   // 0..3: which edge of each quad
    int c8 = lane & 15;                    // 16B chunk (8 bf16) within the 256B row

    float a[8];
    #pragma unroll
    for (int k = 0; k < 8; ++k) a[k] = 0.f;
    float cs = 0.f;

    int2 ee = (lane < 16 && lane < dg) ? ep[lane] : make_int2(0, 0);
    int k = 0;
    for (; k + 16 <= dg; k += 16) {
        int2 een = (lane < 16 && k + 16 + lane < dg) ? ep[k + 16 + lane]
                                                     : make_int2(0, 0);
        #pragma unroll
        for (int j = 0; j < 4; ++j) {
            int eidx = 4 * j + grp;
            int   sj = __shfl(ee.x, eidx, 64);
            float mj = __int_as_float(__shfl(ee.y, eidx, 64));
            uint4 v = *(const uint4*)(xbf + (size_t)sj * D_ + 8 * c8);
            a[0] += bflo(v.x) * mj; a[1] += bfhi(v.x) * mj;
            a[2] += bflo(v.y) * mj; a[3] += bfhi(v.y) * mj;
            a[4] += bflo(v.z) * mj; a[5] += bfhi(v.z) * mj;
            a[6] += bflo(v.w) * mj; a[7] += bfhi(v.w) * mj;
            cs += mj;
        }
        ee = een;
    }
    int rem = dg - k;                      // 0..15
    if (rem > 0) {
        #pragma unroll
        for (int j = 0; j < 4; ++j) {
            int eidx = 4 * j + grp;
            int   sj = __shfl(ee.x, eidx, 64);
            float mj = __int_as_float(__shfl(ee.y, eidx, 64));
            if (eidx < rem) {
                uint4 v = *(const uint4*)(xbf + (size_t)sj * D_ + 8 * c8);
                a[0] += bflo(v.x) * mj; a[1] += bfhi(v.x) * mj;
                a[2] += bflo(v.y) * mj; a[3] += bfhi(v.y) * mj;
                a[4] += bflo(v.z) * mj; a[5] += bfhi(v.z) * mj;
                a[6] += bflo(v.w) * mj; a[7] += bfhi(v.w) * mj;
                cs += mj;
            }
        }
    }

    #pragma unroll
    for (int q = 0; q < 8; ++q) {
        a[q] += __shfl_xor(a[q], 16, 64);
        a[q] += __shfl_xor(a[q], 32, 64);
    }
    cs += __shfl_xor(cs, 16, 64);
    cs += __shfl_xor(cs, 32, 64);

    if (lane < 16) {
        float inv = 1.0f / fmaxf(cs, 1.0f);
        uint4 o;
        o.x = (unsigned int)f2bf(a[0] * inv) | ((unsigned int)f2bf(a[1] * inv) << 16);
        o.y = (unsigned int)f2bf(a[2] * inv) | ((unsigned int)f2bf(a[3] * inv) << 16);
        o.z = (unsigned int)f2bf(a[4] * inv) | ((unsigned int)f2bf(a[5] * inv) << 16);
        o.w = (unsigned int)f2bf(a[6] * inv) | ((unsigned int)f2bf(a[7] * inv) << 16);
        *(uint4*)(agg + (size_t)g * D_ + 8 * c8) = o;
    }
}

// ---------- gemm_ln: MFMA GEMM + ReLU + LN + mask (R15 Phase B, global-staged) ----------
// Grid 8*JB; blk&7 = batch (XCD affinity), blk>>3 = 16-node group within batch.
__global__ __launch_bounds__(256) void gemm_ln_k(
    const unsigned short* __restrict__ xbf, const unsigned short* __restrict__ agg,
    const unsigned short* __restrict__ Bt,
    const float* __restrict__ bself, const float* __restrict__ bnb,
    const float* __restrict__ gamma, const float* __restrict__ beta,
    const float* __restrict__ nmask, float* __restrict__ out)
{
    __shared__ unsigned short xs[16][LDSP];
    __shared__ unsigned short as[16][LDSP];
    __shared__ float red[4][2][16];

    int t = threadIdx.x;
    int lane = t & 63, wv = t >> 6;
    int b = blockIdx.x & 7;
    int j = blockIdx.x >> 3;               // 0..JB-1
    int i0 = j * 16;
    int g0 = b * N_ + i0;
    int limit = N_ - i0; if (limit > 16) limit = 16;

    // Phase A: stage xbf + agg rows into LDS (4 rows/wave each), coalesced.
    #pragma unroll
    for (int lr = wv * 4; lr < wv * 4 + 4; ++lr) {
        unsigned int vx = 0, va = 0;
        if (lr < limit) {
            vx = ((const unsigned int*)(xbf + (size_t)(g0 + lr) * D_))[lane];
            va = ((const unsigned int*)(agg + (size_t)(g0 + lr) * D_))[lane];
        }
        ((unsigned int*)&xs[lr][0])[lane] = vx;
        ((unsigned int*)&as[lr][0])[lane] = va;
    }
    __syncthreads();

    // Phase B: wave wv owns col-tiles 2wv, 2wv+1.
    int quad = lane >> 4;
    int lcol = lane & 15;

    f32x4 acc[2];
    acc[0] = (f32x4)0.0f;
    acc[1] = (f32x4)0.0f;

    #pragma unroll
    for (int kk = 0; kk < 4; ++kk) {
        int kof = kk * 32 + quad * 8;
        bf16x8 a = *(const bf16x8*)&xs[lcol][kof];
        #pragma unroll
        for (int p = 0; p < 2; ++p) {
            int tt = wv * 2 + p;
            bf16x8 bf = *(const bf16x8*)(Bt + (size_t)(tt * 16 + lcol) * 256 + kof);
            acc[p] = __builtin_amdgcn_mfma_f32_16x16x32_bf16(a, bf, acc[p], 0, 0, 0);
        }
    }
    #pragma unroll
    for (int kk = 0; kk < 4; ++kk) {
        int kof = kk * 32 + quad * 8;
        bf16x8 a = *(const bf16x8*)&as[lcol][kof];
        #pragma unroll
        for (int p = 0; p < 2; ++p) {
            int tt = wv * 2 + p;
            bf16x8 bf = *(const bf16x8*)(Bt + (size_t)(tt * 16 + lcol) * 256 + 128 + kof);
            acc[p] = __builtin_amdgcn_mfma_f32_16x16x32_bf16(a, bf, acc[p], 0, 0, 0);
        }
    }

    // bias + ReLU; per-wave 32-col LN partials
    float h[2][4];
    float s[4] = {0, 0, 0, 0}, q[4] = {0, 0, 0, 0};
    float gam[2], bet[2];
    #pragma unroll
    for (int p = 0; p < 2; ++p) {
        int col = (wv * 2 + p) * 16 + lcol;
        float bs = bself[col] + bnb[col];
        gam[p] = gamma[col];
        bet[p] = beta[col];
        #pragma unroll
        for (int r = 0; r < 4; ++r) {
            float v = fmaxf(acc[p][r] + bs, 0.0f);
            h[p][r] = v;
            s[r] += v;
            q[r] += v * v;
        }
    }
    #pragma unroll
    for (int r = 0; r < 4; ++r) {
        #pragma unroll
        for (int off = 1; off <= 8; off <<= 1) {
            s[r] += __shfl_xor(s[r], off, 64);
            q[r] += __shfl_xor(q[r], off, 64);
        }
    }
    if (lcol == 0) {
        #pragma unroll
        for (int r = 0; r < 4; ++r) {
            red[wv][0][quad * 4 + r] = s[r];
            red[wv][1][quad * 4 + r] = q[r];
        }
    }
    __syncthreads();

    #pragma unroll
    for (int r = 0; r < 4; ++r) {
        int row = quad * 4 + r;
        int irow = i0 + row;
        if (irow >= N_) continue;
        float S = red[0][0][row] + red[1][0][row] + red[2][0][row] + red[3][0][row];
        float Q = red[0][1][row] + red[1][1][row] + red[2][1][row] + red[3][1][row];
        float mu = S * (1.0f / D_);
        float var = Q * (1.0f / D_) - mu * mu;
        float rin = rsqrtf(fmaxf(var, 0.0f) + EPS_);
        int g = b * N_ + irow;
        float mk = nmask[g];
        float* op = out + (size_t)g * D_;
        #pragma unroll
        for (int p = 0; p < 2; ++p) {
            int col = (wv * 2 + p) * 16 + lcol;
            op[col] = ((h[p][r] - mu) * rin * gam[p] + bet[p]) * mk;
        }
    }
}

extern "C" void kernel_launch(void* const* d_in, const int* in_sizes, int n_in,
                              void* d_out, int out_size, void* d_ws, size_t ws_size,
                              hipStream_t stream)
{
    const float* x     = (const float*)d_in[0];
    const int*   ei    = (const int*)d_in[1];
    const float* nmask = (const float*)d_in[2];
    const float* em    = (const float*)d_in[3];
    const float* Wself = (const float*)d_in[4];
    const float* bself = (const float*)d_in[5];
    const float* Wnb   = (const float*)d_in[6];
    const float* bnb   = (const float*)d_in[7];
    const float* gamma = (const float*)d_in[8];
    const float* beta  = (const float*)d_in[9];
    float* out = (float*)d_out;

    // ws: cnt int[40000] | entries int2[40000*64] (20.48 MB) | Bt bf16[128*256]
    //     | xbf bf16[40000*128] (10.24 MB) | agg bf16[40000*128] (10.24 MB) ~ 41 MB
    int* cnt = (int*)d_ws;
    int2* entries = (int2*)(cnt + NNODES);                       // byte 160000, 8-al
    unsigned short* Bt = (unsigned short*)(entries + (size_t)NNODES * CAP);
    unsigned short* xbf = Bt + (size_t)128 * 256;                // 16-aligned
    unsigned short* agg = xbf + (size_t)NNODES * D_;             // 16-aligned

    hipMemsetAsync(cnt, 0, NNODES * sizeof(int), stream);
    fill_k<<<FILL_BLOCKS + CONV_BLOCKS + 128, 256, 0, stream>>>(
        ei, em, cnt, entries, x, xbf, Wself, Wnb, Bt);
    gather_k<<<1250 * 8, 256, 0, stream>>>(xbf, cnt, entries, agg);
    gemm_ln_k<<<8 * JB, 256, 0, stream>>>(xbf, agg, Bt,
                                          bself, bnb, gamma, beta, nmask, out);
}

// Round 17
// 167.046 us; speedup vs baseline: 1.0381x; 1.0381x over previous
//
#include <hip/hip_runtime.h>

// GraphSAGE layer: B=8, N=5000, E=100000, D=128. All float tensors f32; edge_index int32.
// R17 pipeline (3 dispatches): memset(cnt) -> fill (XCD-affine buckets, u32-packed
//   entries {src:16|bf16(m):16}, 2 edges/thread + x->bf16 conv + packW)
//   -> fused (bf16 gather -> MFMA gemm [x|agg]@[Ws;Wn] + ReLU+LN+mask).
// R16 post-mortem: ~70us of the window is harness restore/poison (fixed); fill ~40us
// is the largest controllable term. u32 entries halve fill's scattered stores, the
// bucket L2 footprint (1.28 MB/XCD), gather entry bytes, and shfl count (1/edge).

#define B_ 8
#define N_ 5000
#define E_ 100000
#define D_ 128
#define EPS_ 1e-5f
#define NNODES (B_ * N_)   // 40000
#define NEDGES (B_ * E_)   // 800000
#define JB 313             // 16-node blocks per batch (312*16+8 = 5000)
#define PPB ((E_ / 2 + 255) / 256)    // 196 pair-blocks per batch (E even)
#define FILL_BLOCKS (8 * PPB)         // 1568
#define CONV_BLOCKS 2500              // x -> bf16: 2048 elems/block
#define CAP 64             // bucket capacity per node (avg deg 20, P(ovf) ~ 5e-14)
#define LDSP 136           // padded bf16 row stride (272 B -> 2-way bank alias, free)

typedef __bf16 bf16x8 __attribute__((ext_vector_type(8)));
typedef float  f32x4  __attribute__((ext_vector_type(4)));

static __device__ __forceinline__ unsigned short f2bf(float f) {
    union { float f; unsigned int i; } c; c.f = f;
    unsigned int i = c.i;
    i += 0x7fffu + ((i >> 16) & 1u);
    return (unsigned short)(i >> 16);
}
static __device__ __forceinline__ float bflo(unsigned int u) {
    return __uint_as_float(u << 16);
}
static __device__ __forceinline__ float bfhi(unsigned int u) {
    return __uint_as_float(u & 0xffff0000u);
}

// ---------- fill: XCD-affine u32 buckets (0..1567) + x->bf16 (..4067) + packW ----------
__global__ __launch_bounds__(256) void fill_k(
    const int* __restrict__ ei, const float* __restrict__ em,
    int* __restrict__ cnt, unsigned int* __restrict__ entries,
    const float* __restrict__ x, unsigned short* __restrict__ xbf,
    const float* __restrict__ Wself, const float* __restrict__ Wnb,
    unsigned short* __restrict__ Bt)
{
    int blk = blockIdx.x;
    if (blk < FILL_BLOCKS) {
        int b = blk & 7;                    // batch -> XCD (round-robin dispatch)
        int p = (blk >> 3) * 256 + threadIdx.x;
        if (p >= E_ / 2) return;
        int e = 2 * p;                      // pair e, e+1 (E even -> both valid)
        const int* eib = ei + (size_t)b * 2 * E_;
        int2   sv = *(const int2*)(eib + e);
        int2   tv = *(const int2*)(eib + E_ + e);
        float2 mv = *(const float2*)(em + (size_t)b * E_ + e);
        int gb = b * N_;
        if (mv.x != 0.0f) {
            int g = gb + tv.x;
            int slot = atomicAdd(&cnt[g], 1);
            if (slot < CAP)
                entries[((size_t)g << 6) + slot] =
                    (unsigned int)(gb + sv.x) | ((unsigned int)f2bf(mv.x) << 16);
        }
        if (mv.y != 0.0f) {
            int g = gb + tv.y;
            int slot = atomicAdd(&cnt[g], 1);
            if (slot < CAP)
                entries[((size_t)g << 6) + slot] =
                    (unsigned int)(gb + sv.y) | ((unsigned int)f2bf(mv.y) << 16);
        }
    } else if (blk < FILL_BLOCKS + CONV_BLOCKS) {
        size_t base = (size_t)(blk - FILL_BLOCKS) * 2048 + threadIdx.x * 8;
        float4 va = *(const float4*)(x + base);
        float4 vb = *(const float4*)(x + base + 4);
        uint4 o;
        o.x = (unsigned int)f2bf(va.x) | ((unsigned int)f2bf(va.y) << 16);
        o.y = (unsigned int)f2bf(va.z) | ((unsigned int)f2bf(va.w) << 16);
        o.z = (unsigned int)f2bf(vb.x) | ((unsigned int)f2bf(vb.y) << 16);
        o.w = (unsigned int)f2bf(vb.z) | ((unsigned int)f2bf(vb.w) << 16);
        *(uint4*)(xbf + base) = o;
    } else {
        int n = blk - FILL_BLOCKS - CONV_BLOCKS;   // 0..127
        int k = threadIdx.x;                       // 0..255
        float v = (k < 128) ? Wself[(size_t)k * D_ + n]
                            : Wnb[(size_t)(k - 128) * D_ + n];
        Bt[(size_t)n * 256 + k] = f2bf(v);
    }
}

// ---------- gather one node into an LDS row: u32 entries, 1 shfl/edge ----------
static __device__ __forceinline__ void gather_node_lds(
    int g, int lane, const unsigned short* __restrict__ xbf,
    const int* __restrict__ cnt, const unsigned int* __restrict__ entries,
    unsigned short* dst)
{
    int dg = cnt[g]; if (dg > CAP) dg = CAP;
    const unsigned int* ep = entries + ((size_t)g << 6);
    int grp = lane >> 4;                   // 0..3: which edge of each quad
    int c8 = lane & 15;                    // 16B chunk (8 bf16) within the 256B row

    float a[8];
    #pragma unroll
    for (int i = 0; i < 8; ++i) a[i] = 0.f;
    float cs = 0.f;

    unsigned int ee = (lane < 16 && lane < dg) ? ep[lane] : 0u;
    int k = 0;
    for (; k + 16 <= dg; k += 16) {
        unsigned int een = (lane < 16 && k + 16 + lane < dg) ? ep[k + 16 + lane] : 0u;
        #pragma unroll
        for (int j = 0; j < 4; ++j) {
            unsigned int ej = (unsigned int)__shfl((int)ee, 4 * j + grp, 64);
            int   sj = ej & 0xFFFFu;
            float mj = __uint_as_float(ej & 0xFFFF0000u);
            uint4 v = *(const uint4*)(xbf + (size_t)sj * D_ + 8 * c8);
            a[0] += bflo(v.x) * mj; a[1] += bfhi(v.x) * mj;
            a[2] += bflo(v.y) * mj; a[3] += bfhi(v.y) * mj;
            a[4] += bflo(v.z) * mj; a[5] += bfhi(v.z) * mj;
            a[6] += bflo(v.w) * mj; a[7] += bfhi(v.w) * mj;
            cs += mj;
        }
        ee = een;
    }
    int rem = dg - k;                      // 0..15
    if (rem > 0) {
        #pragma unroll
        for (int j = 0; j < 4; ++j) {
            int eidx = 4 * j + grp;
            unsigned int ej = (unsigned int)__shfl((int)ee, eidx, 64);
            int   sj = ej & 0xFFFFu;
            float mj = __uint_as_float(ej & 0xFFFF0000u);
            if (eidx < rem) {
                uint4 v = *(const uint4*)(xbf + (size_t)sj * D_ + 8 * c8);
                a[0] += bflo(v.x) * mj; a[1] += bfhi(v.x) * mj;
                a[2] += bflo(v.y) * mj; a[3] += bfhi(v.y) * mj;
                a[4] += bflo(v.z) * mj; a[5] += bfhi(v.z) * mj;
                a[6] += bflo(v.w) * mj; a[7] += bfhi(v.w) * mj;
                cs += mj;
            }
        }
    }

    #pragma unroll
    for (int q = 0; q < 8; ++q) {
        a[q] += __shfl_xor(a[q], 16, 64);
        a[q] += __shfl_xor(a[q], 32, 64);
    }
    cs += __shfl_xor(cs, 16, 64);
    cs += __shfl_xor(cs, 32, 64);

    if (lane < 16) {
        float inv = 1.0f / fmaxf(cs, 1.0f);
        uint4 o;
        o.x = (unsigned int)f2bf(a[0] * inv) | ((unsigned int)f2bf(a[1] * inv) << 16);
        o.y = (unsigned int)f2bf(a[2] * inv) | ((unsigned int)f2bf(a[3] * inv) << 16);
        o.z = (unsigned int)f2bf(a[4] * inv) | ((unsigned int)f2bf(a[5] * inv) << 16);
        o.w = (unsigned int)f2bf(a[6] * inv) | ((unsigned int)f2bf(a[7] * inv) << 16);
        *(uint4*)(dst + 8 * c8) = o;
    }
}

// ---------- fused gather + MFMA GEMM + ReLU + LN + mask (R13/R15-proven shell) ----------
// Grid 8*JB; blk&7 = batch (XCD affinity), blk>>3 = 16-node group within batch.
__global__ __launch_bounds__(256) void fused_k(
    const unsigned short* __restrict__ xbf, const int* __restrict__ cnt,
    const unsigned int* __restrict__ entries,
    const unsigned short* __restrict__ Bt,
    const float* __restrict__ bself, const float* __restrict__ bnb,
    const float* __restrict__ gamma, const float* __restrict__ beta,
    const float* __restrict__ nmask, float* __restrict__ out)
{
    __shared__ unsigned short xs[16][LDSP];
    __shared__ unsigned short as[16][LDSP];
    __shared__ float red[4][2][16];

    int t = threadIdx.x;
    int lane = t & 63, wv = t >> 6;
    int b = blockIdx.x & 7;
    int j = blockIdx.x >> 3;               // 0..JB-1
    int i0 = j * 16;
    int g0 = b * N_ + i0;
    int limit = N_ - i0; if (limit > 16) limit = 16;

    // Phase A: stage own xbf rows + gathered means into LDS (4 rows/wave each).
    #pragma unroll
    for (int lr = wv * 4; lr < wv * 4 + 4; ++lr) {
        unsigned int v = 0;
        if (lr < limit)
            v = ((const unsigned int*)(xbf + (size_t)(g0 + lr) * D_))[lane];
        ((unsigned int*)&xs[lr][0])[lane] = v;
    }
    for (int lr = wv * 4; lr < wv * 4 + 4; ++lr) {
        if (lr < limit) {
            gather_node_lds(g0 + lr, lane, xbf, cnt, entries, &as[lr][0]);
        } else if (lane < 16) {
            *(uint4*)&as[lr][8 * (lane & 15)] = make_uint4(0u, 0u, 0u, 0u);
        }
    }
    __syncthreads();

    // Phase B: wave wv owns col-tiles 2wv, 2wv+1.
    int quad = lane >> 4;
    int lcol = lane & 15;

    f32x4 acc[2];
    acc[0] = (f32x4)0.0f;
    acc[1] = (f32x4)0.0f;

    #pragma unroll
    for (int kk = 0; kk < 4; ++kk) {
        int kof = kk * 32 + quad * 8;
        bf16x8 a = *(const bf16x8*)&xs[lcol][kof];
        #pragma unroll
        for (int p = 0; p < 2; ++p) {
            int tt = wv * 2 + p;
            bf16x8 bf = *(const bf16x8*)(Bt + (size_t)(tt * 16 + lcol) * 256 + kof);
            acc[p] = __builtin_amdgcn_mfma_f32_16x16x32_bf16(a, bf, acc[p], 0, 0, 0);
        }
    }
    #pragma unroll
    for (int kk = 0; kk < 4; ++kk) {
        int kof = kk * 32 + quad * 8;
        bf16x8 a = *(const bf16x8*)&as[lcol][kof];
        #pragma unroll
        for (int p = 0; p < 2; ++p) {
            int tt = wv * 2 + p;
            bf16x8 bf = *(const bf16x8*)(Bt + (size_t)(tt * 16 + lcol) * 256 + 128 + kof);
            acc[p] = __builtin_amdgcn_mfma_f32_16x16x32_bf16(a, bf, acc[p], 0, 0, 0);
        }
    }

    // bias + ReLU; per-wave 32-col LN partials
    float h[2][4];
    float s[4] = {0, 0, 0, 0}, q[4] = {0, 0, 0, 0};
    float gam[2], bet[2];
    #pragma unroll
    for (int p = 0; p < 2; ++p) {
        int col = (wv * 2 + p) * 16 + lcol;
        float bs = bself[col] + bnb[col];
        gam[p] = gamma[col];
        bet[p] = beta[col];
        #pragma unroll
        for (int r = 0; r < 4; ++r) {
            float v = fmaxf(acc[p][r] + bs, 0.0f);
            h[p][r] = v;
            s[r] += v;
            q[r] += v * v;
        }
    }
    #pragma unroll
    for (int r = 0; r < 4; ++r) {
        #pragma unroll
        for (int off = 1; off <= 8; off <<= 1) {
            s[r] += __shfl_xor(s[r], off, 64);
            q[r] += __shfl_xor(q[r], off, 64);
        }
    }
    if (lcol == 0) {
        #pragma unroll
        for (int r = 0; r < 4; ++r) {
            red[wv][0][quad * 4 + r] = s[r];
            red[wv][1][quad * 4 + r] = q[r];
        }
    }
    __syncthreads();

    #pragma unroll
    for (int r = 0; r < 4; ++r) {
        int row = quad * 4 + r;
        int irow = i0 + row;
        if (irow >= N_) continue;
        float S = red[0][0][row] + red[1][0][row] + red[2][0][row] + red[3][0][row];
        float Q = red[0][1][row] + red[1][1][row] + red[2][1][row] + red[3][1][row];
        float mu = S * (1.0f / D_);
        float var = Q * (1.0f / D_) - mu * mu;
        float rin = rsqrtf(fmaxf(var, 0.0f) + EPS_);
        int g = b * N_ + irow;
        float mk = nmask[g];
        float* op = out + (size_t)g * D_;
        #pragma unroll
        for (int p = 0; p < 2; ++p) {
            int col = (wv * 2 + p) * 16 + lcol;
            op[col] = ((h[p][r] - mu) * rin * gam[p] + bet[p]) * mk;
        }
    }
}

extern "C" void kernel_launch(void* const* d_in, const int* in_sizes, int n_in,
                              void* d_out, int out_size, void* d_ws, size_t ws_size,
                              hipStream_t stream)
{
    const float* x     = (const float*)d_in[0];
    const int*   ei    = (const int*)d_in[1];
    const float* nmask = (const float*)d_in[2];
    const float* em    = (const float*)d_in[3];
    const float* Wself = (const float*)d_in[4];
    const float* bself = (const float*)d_in[5];
    const float* Wnb   = (const float*)d_in[6];
    const float* bnb   = (const float*)d_in[7];
    const float* gamma = (const float*)d_in[8];
    const float* beta  = (const float*)d_in[9];
    float* out = (float*)d_out;

    // ws: cnt int[40000] | entries u32[40000*64] (10.24 MB) | Bt bf16[128*256]
    //     | xbf bf16[40000*128] (10.24 MB)   -> ~21 MB total
    int* cnt = (int*)d_ws;
    unsigned int* entries = (unsigned int*)(cnt + NNODES);       // byte 160000, 4-al
    unsigned short* Bt = (unsigned short*)(entries + (size_t)NNODES * CAP);
    unsigned short* xbf = Bt + (size_t)128 * 256;                // 16-aligned

    hipMemsetAsync(cnt, 0, NNODES * sizeof(int), stream);
    fill_k<<<FILL_BLOCKS + CONV_BLOCKS + 128, 256, 0, stream>>>(
        ei, em, cnt, entries, x, xbf, Wself, Wnb, Bt);
    fused_k<<<8 * JB, 256, 0, stream>>>(xbf, cnt, entries, Bt,
                                        bself, bnb, gamma, beta, nmask, out);
}